// Round 12
// baseline (461.477 us; speedup 1.0000x reference)
//
#include <hip/hip_runtime.h>
#include <hip/hip_bf16.h>
#include <stdint.h>

// ---------------------------------------------------------------------------
// LinearQuantizer: y = fakequant_i8(x, per-tensor) @ fakequant_i8(W, per-row)^T + b
// int8 GEMM via v_mfma_i32_16x16x64_i8. 256x256 tile, BK=64, 2 LDS buffers
// (64 KiB), 1024 threads = 16 waves (4x4 grid, 64x64 out each) -> 4 waves/SIMD
// for TLP (acc[4][4]=64 AGPR + ~55 VGPR fits the 128-reg/wave budget).
// Formal 2-phase schedule (r9's scheme, validated): lgkm(0)-before-barrier
// separates reads from same-buffer stage writes; counted vmcnt(2).
// Zero-conflict swizzle kg^((rA>>1)&3) (r6/r7/r9-measured 0 conflicts).
// prep: fused x-absmax + W quant (r5). quantx: reverse traversal (r10).
// ---------------------------------------------------------------------------

#define QMAX_F 127.0f
#define EPS_F 1e-8f

typedef int v4i __attribute__((ext_vector_type(4)));

static constexpr size_t WSCALE_OFF = 64;
static constexpr size_t XQ_OFF = 1u << 16;

__device__ __forceinline__ int quant1m(float v, float rs) {
    float t = v * rs;
    t = fminf(fmaxf(t, -QMAX_F), QMAX_F);
    return (int)rintf(t);
}

// ---------------- prep: x-absmax (atomicMax) + per-row W quant ----------------
__global__ void prep_kernel(const float4* __restrict__ x, int nx4,
                            const float4* __restrict__ w, int* __restrict__ wq,
                            float* __restrict__ w_scale, int K4,
                            unsigned* __restrict__ amax) {
    const int t = threadIdx.x;  // 256
    const int row = blockIdx.x;

    float xm = 0.0f;
    for (int i = blockIdx.x * 256 + t; i < nx4; i += gridDim.x * 256) {
        float4 v = x[i];
        xm = fmaxf(xm, fmaxf(fmaxf(fabsf(v.x), fabsf(v.y)), fmaxf(fabsf(v.z), fabsf(v.w))));
    }

    const float4* wr = w + (size_t)row * K4;
    float4 vals[4];
    float wm = 0.0f;
    for (int i = 0; i < 4; i++) {
        float4 v = wr[t + 256 * i];
        vals[i] = v;
        wm = fmaxf(wm, fmaxf(fmaxf(fabsf(v.x), fabsf(v.y)), fmaxf(fabsf(v.z), fabsf(v.w))));
    }

    for (int off = 32; off > 0; off >>= 1) {
        xm = fmaxf(xm, __shfl_xor(xm, off));
        wm = fmaxf(wm, __shfl_xor(wm, off));
    }
    __shared__ float sx[4], sw[4];
    if ((t & 63) == 0) { sx[t >> 6] = xm; sw[t >> 6] = wm; }
    __syncthreads();
    float xb = fmaxf(fmaxf(sx[0], sx[1]), fmaxf(sx[2], sx[3]));
    float wb = fmaxf(fmaxf(sw[0], sw[1]), fmaxf(sw[2], sw[3]));
    if (t == 0) atomicMax(amax, __float_as_uint(xb));

    float s = fmaxf(wb / QMAX_F, EPS_F);
    if (t == 0) w_scale[row] = s;
    float rs = 1.0f / s;
    int* wqr = wq + (size_t)row * K4;
    for (int i = 0; i < 4; i++) {
        float4 v = vals[i];
        int q0 = quant1m(v.x, rs), q1 = quant1m(v.y, rs), q2 = quant1m(v.z, rs), q3 = quant1m(v.w, rs);
        wqr[t + 256 * i] = (q0 & 0xff) | ((q1 & 0xff) << 8) | ((q2 & 0xff) << 16) | ((q3 & 0xff) << 24);
    }
}

// ---------------- quantize x -> int8 (reverse order: L3 tail is hot) --------
__global__ void quantx_kernel(const float4* __restrict__ x, const unsigned* __restrict__ amax,
                              int* __restrict__ xq, int n4) {
    float s = fmaxf(__uint_as_float(*amax) / QMAX_F, EPS_F);
    float rs = 1.0f / s;
    int tid = blockIdx.x * blockDim.x + threadIdx.x;
    int stride = gridDim.x * blockDim.x;
    for (int i = n4 - 1 - tid; i >= 0; i -= stride) {
        float4 v = x[i];
        int q0 = quant1m(v.x, rs), q1 = quant1m(v.y, rs), q2 = quant1m(v.z, rs), q3 = quant1m(v.w, rs);
        xq[i] = (q0 & 0xff) | ((q1 & 0xff) << 8) | ((q2 & 0xff) << 16) | ((q3 & 0xff) << 24);
    }
}

// -------- int8 GEMM: 256x256 tile, BK=64, 16 waves, 4 waves/SIMD --------
#define BM 256
#define BN 256
#define BKB 64

static constexpr unsigned BUF_SZ = 32768;  // A 16KB + B 16KB

__device__ __forceinline__ void gload16(const char* g, char* l) {
    __builtin_amdgcn_global_load_lds(
        (const __attribute__((address_space(1))) void*)g,
        (__attribute__((address_space(3))) void*)l, 16, 0, 0);
}

__global__ __launch_bounds__(1024, 1) void gemm_i8_16w(
    const char* __restrict__ xq, const char* __restrict__ wq,
    const float* __restrict__ w_scale, const unsigned* __restrict__ amax,
    const float* __restrict__ bias, float* __restrict__ out,
    int M, int N, int K) {
    // LDS: 2 bufs x { A[256][64] 16KB + B[256][64] 16KB } = 64 KiB
    __shared__ __align__(16) char lds[2 * BUF_SZ];

    // XCD-aware bijective swizzle (nwg = 1024, % 8 == 0)
    const int nwg = gridDim.x, bid = blockIdx.x;
    const int cpx = nwg >> 3;
    const int swz = (bid & 7) * cpx + (bid >> 3);
    const int nbm = M / BM;
    const int bm = swz % nbm, bn = swz / nbm;

    const int t = threadIdx.x;
    const int lane = t & 63, wid = t >> 6;
    const int wr = wid >> 2, wc = wid & 3;  // 4x4 waves; wave out = 64x64

    // ---- staging: linear LDS dest (t*16), pre-swizzled global source col ----
    // swizzle: col16' = col16 ^ ((row>>1)&3)  (involution, 64B rows)
    const int srow = t >> 2;                        // 0..255
    const int scol = ((t & 3) ^ ((srow >> 1) & 3)) << 4;
    const char* aSrc = xq + (size_t)(bm * BM + srow) * K + scol;
    const char* bSrc = wq + (size_t)(bn * BN + srow) * K + scol;
    char* ldsT = lds + t * 16;  // 1024 threads x 16B = 16KB per gload round

    auto stage = [&](unsigned bufOff, int ktc) {  // 2 gloads: A 16KB + B 16KB
        gload16(aSrc + ktc, ldsT + bufOff);
        gload16(bSrc + ktc, ldsT + bufOff + 16384u);
    };

    // ---- ds_read addressing (zero-conflict pattern, 64B rows) ----
    const int rA = lane & 15, kg = lane >> 4;
    const unsigned cks = (unsigned)((kg ^ ((rA >> 1) & 3)) << 4);
    // a[m]: bb + wr*4096 + (16m+rA)*64 + cks
    const unsigned aB = ((unsigned)wr << 12) + ((unsigned)rA << 6) + cks;
    // b[n]: bb + 16384 + wc*4096 + (16n+rA)*64 + cks
    const unsigned bB = 16384u + ((unsigned)wc << 12) + ((unsigned)rA << 6) + cks;

    v4i acc[4][4];
#pragma unroll
    for (int m = 0; m < 4; m++)
#pragma unroll
        for (int n = 0; n < 4; n++) acc[m][n] = (v4i){0, 0, 0, 0};

    const int nkt = K / BKB;  // 64

    // ---- prologue: stage tiles 0 and 1 ----
    stage(0u, 0);
    {
        const int k1 = (1 < nkt) ? BKB : 0;
        stage(BUF_SZ, k1);
    }
    asm volatile("s_waitcnt vmcnt(2)" ::: "memory");  // tile0's 2 loads retired
    __builtin_amdgcn_s_barrier();

    for (int T = 0; T < nkt; ++T) {
        const unsigned bb = (T & 1) ? BUF_SZ : 0u;
        const int kT2 = (T + 2 < nkt) ? (T + 2) * BKB : 0;  // clamped: always issue
        v4i a[4], b[4];

        // ===== ph1: read a[0..3] + b[0..3] (8); lgkm(0); barrier; MFMA n0-1 =====
        // lgkm(0) BEFORE the barrier: once all waves pass it, every read of bb
        // is complete -> ph2's stage writes into bb cannot race (formal).
#pragma unroll
        for (int m = 0; m < 4; m++)
            a[m] = *(const v4i*)(lds + bb + aB + ((unsigned)m << 10));
#pragma unroll
        for (int n = 0; n < 4; n++)
            b[n] = *(const v4i*)(lds + bb + bB + ((unsigned)n << 10));
        asm volatile("s_waitcnt lgkmcnt(0)" ::: "memory");
        __builtin_amdgcn_s_barrier();
        __builtin_amdgcn_sched_barrier(0);
        __builtin_amdgcn_s_setprio(1);
#pragma unroll
        for (int n = 0; n < 2; n++)
#pragma unroll
            for (int m = 0; m < 4; m++)
                acc[m][n] = __builtin_amdgcn_mfma_i32_16x16x64_i8(a[m], b[n], acc[m][n], 0, 0, 0);
        __builtin_amdgcn_s_setprio(0);
        // no post-MFMA barrier: drift-by-one allowed

        // ===== ph2: stage tile T+2 into bb; vmcnt(2); barrier; MFMA n2-3 =====
        stage(bb, kT2);
        asm volatile("s_waitcnt vmcnt(2)" ::: "memory");  // retires tile T+1's 2
        __builtin_amdgcn_s_barrier();
        __builtin_amdgcn_s_setprio(1);
#pragma unroll
        for (int n = 2; n < 4; n++)
#pragma unroll
            for (int m = 0; m < 4; m++)
                acc[m][n] = __builtin_amdgcn_mfma_i32_16x16x64_i8(a[m], b[n], acc[m][n], 0, 0, 0);
        __builtin_amdgcn_s_setprio(0);
        // no post-MFMA barrier: next ph1 reads ~bb (resident via vmcnt above);
        // next writes to ~bb only issue after next ph1's barrier (formal).
    }

    // ---- epilogue: y = acc * (a_scale * w_scale[col]) + bias[col] ----
    float a_s = fmaxf(__uint_as_float(*amax) / QMAX_F, EPS_F);
    const int row0 = bm * BM + wr * 64 + (kg << 2);
    const int col0 = bn * BN + wc * 64 + rA;
#pragma unroll
    for (int n = 0; n < 4; n++) {
        int col = col0 + n * 16;
        float f = a_s * w_scale[col];
        float bv = bias[col];
#pragma unroll
        for (int m = 0; m < 4; m++) {
            size_t base = (size_t)(row0 + m * 16) * N + col;
#pragma unroll
            for (int j = 0; j < 4; j++)
                out[base + (size_t)j * N] = (float)acc[m][n][j] * f + bv;
        }
    }
}

extern "C" void kernel_launch(void* const* d_in, const int* in_sizes, int n_in,
                              void* d_out, int out_size, void* d_ws, size_t ws_size,
                              hipStream_t stream) {
    const float* x = (const float*)d_in[0];
    const float* w = (const float*)d_in[1];
    const float* bias = (const float*)d_in[2];
    float* out = (float*)d_out;

    const int N = in_sizes[2];      // 4096
    const int K = in_sizes[1] / N;  // 4096
    const int M = in_sizes[0] / K;  // 16384

    char* ws = (char*)d_ws;
    unsigned* amax = (unsigned*)ws;
    float* w_scale = (float*)(ws + WSCALE_OFF);
    char* xq = ws + XQ_OFF;
    char* wq = ws + XQ_OFF + (size_t)M * K;

    size_t needed = XQ_OFF + (size_t)M * K + (size_t)N * K;
    if (ws_size < needed) return;

    hipMemsetAsync(amax, 0, 4, stream);

    int n4x = (M * K) / 4;
    prep_kernel<<<N, 256, 0, stream>>>((const float4*)x, n4x, (const float4*)w,
                                       (int*)wq, w_scale, K / 4, amax);
    quantx_kernel<<<2048, 256, 0, stream>>>((const float4*)x, amax, (int*)xq, n4x);

    int grid = (M / BM) * (N / BN);  // 64*16 = 1024
    gemm_i8_16w<<<grid, 1024, 0, stream>>>(xq, wq, w_scale, amax, bias, out, M, N, K);
}

// Round 13
// 447.096 us; speedup vs baseline: 1.0322x; 1.0322x over previous
//
#include <hip/hip_runtime.h>
#include <hip/hip_bf16.h>
#include <stdint.h>

// ---------------------------------------------------------------------------
// LinearQuantizer: y = fakequant_i8(x, per-tensor) @ fakequant_i8(W, per-row)^T + b
// GEMM: r4 champion schedule (256x256, 4-phase drift-by-one, T2 swizzle,
// counted vmcnt(6), setprio) with v_mfma_i32_32x32x32_i8 (half the MFMA
// instruction count, +12% ceiling). Single-variable A/B vs r10/r11.
// prep: fused x-absmax + W quant (r5). quantx: reverse traversal (r10).
// ---------------------------------------------------------------------------

#define QMAX_F 127.0f
#define EPS_F 1e-8f

typedef int v4i __attribute__((ext_vector_type(4)));
typedef int v16i __attribute__((ext_vector_type(16)));

static constexpr size_t WSCALE_OFF = 64;
static constexpr size_t XQ_OFF = 1u << 16;

__device__ __forceinline__ int quant1m(float v, float rs) {
    float t = v * rs;
    t = fminf(fmaxf(t, -QMAX_F), QMAX_F);
    return (int)rintf(t);
}

// ---------------- prep: x-absmax (atomicMax) + per-row W quant ----------------
__global__ void prep_kernel(const float4* __restrict__ x, int nx4,
                            const float4* __restrict__ w, int* __restrict__ wq,
                            float* __restrict__ w_scale, int K4,
                            unsigned* __restrict__ amax) {
    const int t = threadIdx.x;  // 256
    const int row = blockIdx.x;

    float xm = 0.0f;
    for (int i = blockIdx.x * 256 + t; i < nx4; i += gridDim.x * 256) {
        float4 v = x[i];
        xm = fmaxf(xm, fmaxf(fmaxf(fabsf(v.x), fabsf(v.y)), fmaxf(fabsf(v.z), fabsf(v.w))));
    }

    const float4* wr = w + (size_t)row * K4;
    float4 vals[4];
    float wm = 0.0f;
    for (int i = 0; i < 4; i++) {
        float4 v = wr[t + 256 * i];
        vals[i] = v;
        wm = fmaxf(wm, fmaxf(fmaxf(fabsf(v.x), fabsf(v.y)), fmaxf(fabsf(v.z), fabsf(v.w))));
    }

    for (int off = 32; off > 0; off >>= 1) {
        xm = fmaxf(xm, __shfl_xor(xm, off));
        wm = fmaxf(wm, __shfl_xor(wm, off));
    }
    __shared__ float sx[4], sw[4];
    if ((t & 63) == 0) { sx[t >> 6] = xm; sw[t >> 6] = wm; }
    __syncthreads();
    float xb = fmaxf(fmaxf(sx[0], sx[1]), fmaxf(sx[2], sx[3]));
    float wb = fmaxf(fmaxf(sw[0], sw[1]), fmaxf(sw[2], sw[3]));
    if (t == 0) atomicMax(amax, __float_as_uint(xb));

    float s = fmaxf(wb / QMAX_F, EPS_F);
    if (t == 0) w_scale[row] = s;
    float rs = 1.0f / s;
    int* wqr = wq + (size_t)row * K4;
    for (int i = 0; i < 4; i++) {
        float4 v = vals[i];
        int q0 = quant1m(v.x, rs), q1 = quant1m(v.y, rs), q2 = quant1m(v.z, rs), q3 = quant1m(v.w, rs);
        wqr[t + 256 * i] = (q0 & 0xff) | ((q1 & 0xff) << 8) | ((q2 & 0xff) << 16) | ((q3 & 0xff) << 24);
    }
}

// ---------------- quantize x -> int8 (reverse order: L3 tail is hot) --------
__global__ void quantx_kernel(const float4* __restrict__ x, const unsigned* __restrict__ amax,
                              int* __restrict__ xq, int n4) {
    float s = fmaxf(__uint_as_float(*amax) / QMAX_F, EPS_F);
    float rs = 1.0f / s;
    int tid = blockIdx.x * blockDim.x + threadIdx.x;
    int stride = gridDim.x * blockDim.x;
    for (int i = n4 - 1 - tid; i >= 0; i -= stride) {
        float4 v = x[i];
        int q0 = quant1m(v.x, rs), q1 = quant1m(v.y, rs), q2 = quant1m(v.z, rs), q3 = quant1m(v.w, rs);
        xq[i] = (q0 & 0xff) | ((q1 & 0xff) << 8) | ((q2 & 0xff) << 16) | ((q3 & 0xff) << 24);
    }
}

// -------- int8 GEMM, 256x256 tile, 4-phase drift-by-one, 32x32x32 MFMA -------
#define BM 256
#define BN 256
#define BKB 128  // K-bytes (=elements) per K-tile

__device__ __forceinline__ void gload16(const char* g, char* l) {
    __builtin_amdgcn_global_load_lds(
        (const __attribute__((address_space(1))) void*)g,
        (__attribute__((address_space(3))) void*)l, 16, 0, 0);
}

__global__ __launch_bounds__(512, 2) void gemm_i8_32(
    const char* __restrict__ xq, const char* __restrict__ wq,
    const float* __restrict__ w_scale, const unsigned* __restrict__ amax,
    const float* __restrict__ bias, float* __restrict__ out,
    int M, int N, int K) {
    // LDS: [buf 2][op 2 (A,B)][half 2][row 128][col 128B] = 128 KiB
    __shared__ __align__(16) char lds[131072];

    // XCD-aware bijective swizzle (nwg = 1024, % 8 == 0)
    const int nwg = gridDim.x, bid = blockIdx.x;
    const int cpx = nwg >> 3;
    const int swz = (bid & 7) * cpx + (bid >> 3);
    const int nbm = M / BM;
    const int bm = swz % nbm, bn = swz / nbm;

    const int t = threadIdx.x;
    const int lane = t & 63, wid = t >> 6;
    const int wr = wid >> 2, wc = wid & 3;  // 2 (M) x 4 (N) waves; wave out = 128x64

    // ---- staging: linear LDS dest (t*16), pre-swizzled global source col ----
    const int srow = t >> 3;
    const int scol = ((t & 7) ^ (srow & 7)) << 4;
    const char* aSrc = xq + (size_t)(bm * BM + srow) * K + scol;
    const char* bSrc = wq + (size_t)(bn * BN + srow) * K + scol;
    char* ldsT = lds + t * 16;

    auto stageA = [&](int half, int tt, int ktc) {
        char* d = ldsT + ((unsigned)(tt & 1) << 16) + ((unsigned)half << 14);
        gload16(aSrc + (size_t)(half * 128) * K + ktc, d);
        gload16(aSrc + (size_t)(half * 128 + 64) * K + ktc, d + 8192);
    };
    auto stageB = [&](int half, int tt, int ktc) {
        char* d = ldsT + ((unsigned)(tt & 1) << 16) + 32768u + ((unsigned)half << 14);
        gload16(bSrc + (size_t)(half * 128) * K + ktc, d);
        gload16(bSrc + (size_t)(half * 128 + 64) * K + ktc, d + 8192);
    };

    // ---- ds_read addressing for 32x32x32 frags (r3-verified layout) ----
    // lane: row/col = lane&31, k-half = lane>>5; swizzle byte ^= ((row&7)<<4)
    const int r32 = lane & 31, kh = lane >> 5, sw7 = r32 & 7;
    unsigned cks[4];
#pragma unroll
    for (int ks = 0; ks < 4; ks++) cks[ks] = (unsigned)(((2 * ks + kh) ^ sw7) << 4);
    // A frag (mi,ks): bb + wr*16384 + [mh1? +8192] + (mi&1)*4096 + r32*128 + cks
    const unsigned aB = ((unsigned)wr << 14) + ((unsigned)r32 << 7);
    // B frag (ni,ks): bb + 32768 + wc*8192 + ni*4096 + r32*128 + cks
    const unsigned bB = 32768u + ((unsigned)wc << 13) + ((unsigned)r32 << 7);

    v16i acc[4][2];
#pragma unroll
    for (int mi = 0; mi < 4; mi++)
#pragma unroll
        for (int ni = 0; ni < 2; ni++)
#pragma unroll
            for (int r = 0; r < 16; r++) acc[mi][ni][r] = 0;

    const int nkt = K / BKB;  // 32

    // ---- prologue: tile0 fully + 3 half-tiles of tile1 ----
    stageA(0, 0, 0); stageA(1, 0, 0); stageB(0, 0, 0); stageB(1, 0, 0);
    {
        const int k1 = (1 < nkt) ? BKB : 0;
        stageB(0, 1, k1); stageA(0, 1, k1); stageB(1, 1, k1);
    }
    asm volatile("s_waitcnt vmcnt(6)" ::: "memory");  // tile0's 8 loads retired
    __builtin_amdgcn_s_barrier();

    for (int T = 0; T < nkt; ++T) {
        const unsigned bb = (unsigned)(T & 1) << 16;
        const int kA1 = (T + 1 < nkt) ? (T + 1) * BKB : 0;  // clamped: loads always issue
        const int kT2 = (T + 2 < nkt) ? (T + 2) * BKB : 0;
        v4i a[2][4], b0[4], b1[4];

        // ===== ph1: read A mi0-1 (8) + B ni0 (4); stage A-h1(T+1); MFMA q(0,0) =====
#pragma unroll
        for (int mi = 0; mi < 2; mi++)
#pragma unroll
            for (int ks = 0; ks < 4; ks++)
                a[mi][ks] = *(const v4i*)(lds + bb + aB + ((unsigned)mi << 12) + cks[ks]);
#pragma unroll
        for (int ks = 0; ks < 4; ks++)
            b0[ks] = *(const v4i*)(lds + bb + bB + cks[ks]);
        stageA(1, T + 1, kA1);
        __builtin_amdgcn_s_barrier();
        asm volatile("s_waitcnt lgkmcnt(0)" ::: "memory");
        __builtin_amdgcn_sched_barrier(0);
        __builtin_amdgcn_s_setprio(1);
#pragma unroll
        for (int ks = 0; ks < 4; ks++)
#pragma unroll
            for (int mi = 0; mi < 2; mi++)
                acc[mi][0] = __builtin_amdgcn_mfma_i32_32x32x32_i8(a[mi][ks], b0[ks], acc[mi][0], 0, 0, 0);
        __builtin_amdgcn_s_setprio(0);
        // (no post-MFMA barrier: waves may drift into ph2)

        // ===== ph2: read B ni1 (4); MFMA q(0,1) =====
#pragma unroll
        for (int ks = 0; ks < 4; ks++)
            b1[ks] = *(const v4i*)(lds + bb + bB + 4096u + cks[ks]);
        __builtin_amdgcn_s_barrier();
        asm volatile("s_waitcnt lgkmcnt(0)" ::: "memory");
        __builtin_amdgcn_sched_barrier(0);
        __builtin_amdgcn_s_setprio(1);
#pragma unroll
        for (int ks = 0; ks < 4; ks++)
#pragma unroll
            for (int mi = 0; mi < 2; mi++)
                acc[mi][1] = __builtin_amdgcn_mfma_i32_32x32x32_i8(a[mi][ks], b1[ks], acc[mi][1], 0, 0, 0);
        __builtin_amdgcn_s_setprio(0);

        // ===== ph3: read A mi2-3 (8); MFMA q(1,1) =====
#pragma unroll
        for (int mi = 0; mi < 2; mi++)
#pragma unroll
            for (int ks = 0; ks < 4; ks++)
                a[mi][ks] = *(const v4i*)(lds + bb + aB + 8192u + ((unsigned)mi << 12) + cks[ks]);
        __builtin_amdgcn_s_barrier();
        asm volatile("s_waitcnt lgkmcnt(0)" ::: "memory");
        __builtin_amdgcn_sched_barrier(0);
        __builtin_amdgcn_s_setprio(1);
#pragma unroll
        for (int ks = 0; ks < 4; ks++)
#pragma unroll
            for (int mi = 0; mi < 2; mi++)
                acc[2 + mi][1] = __builtin_amdgcn_mfma_i32_32x32x32_i8(a[mi][ks], b1[ks], acc[2 + mi][1], 0, 0, 0);
        __builtin_amdgcn_s_setprio(0);

        // ===== ph4: stage B-h0+A-h0+B-h1(T+2); vmcnt(6); MFMA q(1,0) =====
        stageB(0, T + 2, kT2);
        stageA(0, T + 2, kT2);
        stageB(1, T + 2, kT2);
        asm volatile("s_waitcnt vmcnt(6)" ::: "memory");  // retires all of tile T+1
        __builtin_amdgcn_s_barrier();
        __builtin_amdgcn_s_setprio(1);
#pragma unroll
        for (int ks = 0; ks < 4; ks++)
#pragma unroll
            for (int mi = 0; mi < 2; mi++)
                acc[2 + mi][0] = __builtin_amdgcn_mfma_i32_32x32x32_i8(a[mi][ks], b0[ks], acc[2 + mi][0], 0, 0, 0);
        __builtin_amdgcn_s_setprio(0);
        // (no post-MFMA barrier: next ph1's reads of T+1 are safe — vmcnt(6)
        //  before this phase's collective barrier retired all of tile T+1)
    }

    // ---- epilogue: direct scalar stores, 32x32 C/D mapping (r3-verified):
    //      col = lane&31 (+ni*32), row = (r&3) + 8*(r>>2) + 4*kh (+mi*32) ----
    float a_s = fmaxf(__uint_as_float(*amax) / QMAX_F, EPS_F);
    const int row0 = bm * BM + wr * 128;
    const int col0 = bn * BN + wc * 64 + r32;
#pragma unroll
    for (int ni = 0; ni < 2; ni++) {
        int col = col0 + ni * 32;
        float f = a_s * w_scale[col];
        float bv = bias[col];
#pragma unroll
        for (int mi = 0; mi < 4; mi++) {
#pragma unroll
            for (int r = 0; r < 16; r++) {
                int row = row0 + mi * 32 + (r & 3) + 8 * (r >> 2) + 4 * kh;
                out[(size_t)row * N + col] = (float)acc[mi][ni][r] * f + bv;
            }
        }
    }
}

extern "C" void kernel_launch(void* const* d_in, const int* in_sizes, int n_in,
                              void* d_out, int out_size, void* d_ws, size_t ws_size,
                              hipStream_t stream) {
    const float* x = (const float*)d_in[0];
    const float* w = (const float*)d_in[1];
    const float* bias = (const float*)d_in[2];
    float* out = (float*)d_out;

    const int N = in_sizes[2];      // 4096
    const int K = in_sizes[1] / N;  // 4096
    const int M = in_sizes[0] / K;  // 16384

    char* ws = (char*)d_ws;
    unsigned* amax = (unsigned*)ws;
    float* w_scale = (float*)(ws + WSCALE_OFF);
    char* xq = ws + XQ_OFF;
    char* wq = ws + XQ_OFF + (size_t)M * K;

    size_t needed = XQ_OFF + (size_t)M * K + (size_t)N * K;
    if (ws_size < needed) return;

    hipMemsetAsync(amax, 0, 4, stream);

    int n4x = (M * K) / 4;
    prep_kernel<<<N, 256, 0, stream>>>((const float4*)x, n4x, (const float4*)w,
                                       (int*)wq, w_scale, K / 4, amax);
    quantx_kernel<<<2048, 256, 0, stream>>>((const float4*)x, amax, (int*)xq, n4x);

    int grid = (M / BM) * (N / BN);  // 64*16 = 1024
    gemm_i8_32<<<grid, 512, 0, stream>>>(xq, wq, w_scale, amax, bias, out, M, N, K);
}

// Round 14
// 426.943 us; speedup vs baseline: 1.0809x; 1.0472x over previous
//
#include <hip/hip_runtime.h>
#include <hip/hip_bf16.h>
#include <stdint.h>

// ---------------------------------------------------------------------------
// LinearQuantizer: y = fakequant_i8(x, per-tensor) @ fakequant_i8(W, per-row)^T + b
// FINAL CHAMPION (r11 config, restored after r13 shape-probe regression):
//   GEMM: v_mfma_i32_16x16x64_i8, 256x256 tile, 8 waves, 4-phase
//   drift-by-one schedule, T2 zero-conflict swizzle, counted vmcnt(6),
//   setprio around MFMA clusters. ~280us, MfmaUtil ~43%, 0 bank conflicts.
//   prep: fused x-absmax + per-row W quant. quantx: reverse traversal.
// Probed-and-rejected axes: barrier count (r2,r8), wait splitting (r5,r11),
// waves/SIMD 1 & 4 (r7,r12), tile 512/128 (r6,r9), MFMA 32x32 (r3,r13).
// ---------------------------------------------------------------------------

#define QMAX_F 127.0f
#define EPS_F 1e-8f

typedef int v4i __attribute__((ext_vector_type(4)));

static constexpr size_t WSCALE_OFF = 64;
static constexpr size_t XQ_OFF = 1u << 16;

__device__ __forceinline__ int quant1m(float v, float rs) {
    float t = v * rs;
    t = fminf(fmaxf(t, -QMAX_F), QMAX_F);
    return (int)rintf(t);
}

// ---------------- prep: x-absmax (atomicMax) + per-row W quant ----------------
__global__ void prep_kernel(const float4* __restrict__ x, int nx4,
                            const float4* __restrict__ w, int* __restrict__ wq,
                            float* __restrict__ w_scale, int K4,
                            unsigned* __restrict__ amax) {
    const int t = threadIdx.x;  // 256
    const int row = blockIdx.x;

    float xm = 0.0f;
    for (int i = blockIdx.x * 256 + t; i < nx4; i += gridDim.x * 256) {
        float4 v = x[i];
        xm = fmaxf(xm, fmaxf(fmaxf(fabsf(v.x), fabsf(v.y)), fmaxf(fabsf(v.z), fabsf(v.w))));
    }

    const float4* wr = w + (size_t)row * K4;
    float4 vals[4];
    float wm = 0.0f;
    for (int i = 0; i < 4; i++) {
        float4 v = wr[t + 256 * i];
        vals[i] = v;
        wm = fmaxf(wm, fmaxf(fmaxf(fabsf(v.x), fabsf(v.y)), fmaxf(fabsf(v.z), fabsf(v.w))));
    }

    for (int off = 32; off > 0; off >>= 1) {
        xm = fmaxf(xm, __shfl_xor(xm, off));
        wm = fmaxf(wm, __shfl_xor(wm, off));
    }
    __shared__ float sx[4], sw[4];
    if ((t & 63) == 0) { sx[t >> 6] = xm; sw[t >> 6] = wm; }
    __syncthreads();
    float xb = fmaxf(fmaxf(sx[0], sx[1]), fmaxf(sx[2], sx[3]));
    float wb = fmaxf(fmaxf(sw[0], sw[1]), fmaxf(sw[2], sw[3]));
    if (t == 0) atomicMax(amax, __float_as_uint(xb));

    float s = fmaxf(wb / QMAX_F, EPS_F);
    if (t == 0) w_scale[row] = s;
    float rs = 1.0f / s;
    int* wqr = wq + (size_t)row * K4;
    for (int i = 0; i < 4; i++) {
        float4 v = vals[i];
        int q0 = quant1m(v.x, rs), q1 = quant1m(v.y, rs), q2 = quant1m(v.z, rs), q3 = quant1m(v.w, rs);
        wqr[t + 256 * i] = (q0 & 0xff) | ((q1 & 0xff) << 8) | ((q2 & 0xff) << 16) | ((q3 & 0xff) << 24);
    }
}

// ---------------- quantize x -> int8 (reverse order: L3 tail is hot) --------
__global__ void quantx_kernel(const float4* __restrict__ x, const unsigned* __restrict__ amax,
                              int* __restrict__ xq, int n4) {
    float s = fmaxf(__uint_as_float(*amax) / QMAX_F, EPS_F);
    float rs = 1.0f / s;
    int tid = blockIdx.x * blockDim.x + threadIdx.x;
    int stride = gridDim.x * blockDim.x;
    for (int i = n4 - 1 - tid; i >= 0; i -= stride) {
        float4 v = x[i];
        int q0 = quant1m(v.x, rs), q1 = quant1m(v.y, rs), q2 = quant1m(v.z, rs), q3 = quant1m(v.w, rs);
        xq[i] = (q0 & 0xff) | ((q1 & 0xff) << 8) | ((q2 & 0xff) << 16) | ((q3 & 0xff) << 24);
    }
}

// ---------------- int8 GEMM, 256x256 tile, 4-phase drift-by-one -------------
#define BM 256
#define BN 256
#define BKB 128  // K-bytes (=elements) per K-tile

__device__ __forceinline__ void gload16(const char* g, char* l) {
    __builtin_amdgcn_global_load_lds(
        (const __attribute__((address_space(1))) void*)g,
        (__attribute__((address_space(3))) void*)l, 16, 0, 0);
}

__global__ __launch_bounds__(512, 2) void gemm_i8_8ph(
    const char* __restrict__ xq, const char* __restrict__ wq,
    const float* __restrict__ w_scale, const unsigned* __restrict__ amax,
    const float* __restrict__ bias, float* __restrict__ out,
    int M, int N, int K) {
    // LDS: [buf 2][op 2 (A,B)][half 2][row 128][col 128B] = 128 KiB
    __shared__ __align__(16) char lds[131072];

    // XCD-aware bijective swizzle (nwg = 1024, % 8 == 0)
    const int nwg = gridDim.x, bid = blockIdx.x;
    const int cpx = nwg >> 3;
    const int swz = (bid & 7) * cpx + (bid >> 3);
    const int nbm = M / BM;
    const int bm = swz % nbm, bn = swz / nbm;

    const int t = threadIdx.x;
    const int lane = t & 63, wid = t >> 6;
    const int wr = wid >> 2, wc = wid & 3;  // 2 (M) x 4 (N) waves; wave out = 128x64

    // ---- staging: linear LDS dest (t*16), pre-swizzled global source col ----
    const int srow = t >> 3;
    const int scol = ((t & 7) ^ (srow & 7)) << 4;
    const char* aSrc = xq + (size_t)(bm * BM + srow) * K + scol;
    const char* bSrc = wq + (size_t)(bn * BN + srow) * K + scol;
    char* ldsT = lds + t * 16;

    auto stageA = [&](int half, int tt, int ktc) {
        char* d = ldsT + ((unsigned)(tt & 1) << 16) + ((unsigned)half << 14);
        gload16(aSrc + (size_t)(half * 128) * K + ktc, d);
        gload16(aSrc + (size_t)(half * 128 + 64) * K + ktc, d + 8192);
    };
    auto stageB = [&](int half, int tt, int ktc) {
        char* d = ldsT + ((unsigned)(tt & 1) << 16) + 32768u + ((unsigned)half << 14);
        gload16(bSrc + (size_t)(half * 128) * K + ktc, d);
        gload16(bSrc + (size_t)(half * 128 + 64) * K + ktc, d + 8192);
    };

    // ---- ds_read addressing (swizzled col: byte ^= ((row&7)<<4)) ----
    const int rA = lane & 15, kg = lane >> 4, sw7 = lane & 7;
    const unsigned cks0 = (unsigned)((kg ^ sw7) << 4);
    const unsigned cks1 = (unsigned)(((4 + kg) ^ sw7) << 4);
    const unsigned aBase = ((unsigned)wr << 14) + ((unsigned)rA << 7);
    const unsigned bBase = 32768u + ((unsigned)wc << 13) + ((unsigned)rA << 7);

    v4i acc[8][4];
#pragma unroll
    for (int m = 0; m < 8; m++)
#pragma unroll
        for (int n = 0; n < 4; n++) acc[m][n] = (v4i){0, 0, 0, 0};

    const int nkt = K / BKB;  // 32

    // ---- prologue: tile0 fully + 3 half-tiles of tile1 ----
    stageA(0, 0, 0); stageA(1, 0, 0); stageB(0, 0, 0); stageB(1, 0, 0);
    {
        const int k1 = (1 < nkt) ? BKB : 0;
        stageB(0, 1, k1); stageA(0, 1, k1); stageB(1, 1, k1);
    }
    asm volatile("s_waitcnt vmcnt(6)" ::: "memory");  // tile0's 8 loads retired
    __builtin_amdgcn_s_barrier();

    for (int T = 0; T < nkt; ++T) {
        const unsigned bb = (unsigned)(T & 1) << 16;
        const int kA1 = (T + 1 < nkt) ? (T + 1) * BKB : 0;  // clamped: loads always issue
        const int kT2 = (T + 2 < nkt) ? (T + 2) * BKB : 0;
        v4i a[4][2], b0[2][2], b1[2][2];

        // ===== ph1: read A-mh0(8)+B-nh0(4), then b1(4) pinned LAST; stage
        //        A-h1(T+1); barrier; lgkm(4) -> a0+b0 ready, b1 in flight;
        //        MFMA q(0,0) hides b1's latency. =====
#pragma unroll
        for (int m = 0; m < 4; m++) {
            a[m][0] = *(const v4i*)(lds + bb + aBase + ((unsigned)m << 11) + cks0);
            a[m][1] = *(const v4i*)(lds + bb + aBase + ((unsigned)m << 11) + cks1);
        }
#pragma unroll
        for (int n = 0; n < 2; n++) {
            b0[n][0] = *(const v4i*)(lds + bb + bBase + ((unsigned)n << 11) + cks0);
            b0[n][1] = *(const v4i*)(lds + bb + bBase + ((unsigned)n << 11) + cks1);
        }
        __builtin_amdgcn_sched_barrier(0);  // pin: first 12 reads before b1's 4
#pragma unroll
        for (int n = 0; n < 2; n++) {
            b1[n][0] = *(const v4i*)(lds + bb + bBase + 4096u + ((unsigned)n << 11) + cks0);
            b1[n][1] = *(const v4i*)(lds + bb + bBase + 4096u + ((unsigned)n << 11) + cks1);
        }
        stageA(1, T + 1, kA1);
        __builtin_amdgcn_s_barrier();
        asm volatile("s_waitcnt lgkmcnt(4)" ::: "memory");  // a0,b0 done; b1 in flight
        __builtin_amdgcn_sched_barrier(0);
        __builtin_amdgcn_s_setprio(1);
#pragma unroll
        for (int ks = 0; ks < 2; ks++)
#pragma unroll
            for (int m = 0; m < 4; m++)
#pragma unroll
                for (int n = 0; n < 2; n++)
                    acc[m][n] = __builtin_amdgcn_mfma_i32_16x16x64_i8(a[m][ks], b0[n][ks], acc[m][n], 0, 0, 0);
        __builtin_amdgcn_s_setprio(0);
        // (no post-MFMA barrier: waves may drift into ph2)

        // ===== ph2: read-free. barrier; lgkm(0) (b1 already landed);
        //        MFMA q(0,1); then issue ph3's A-mh1 reads into a[]. =====
        __builtin_amdgcn_s_barrier();
        asm volatile("s_waitcnt lgkmcnt(0)" ::: "memory");
        __builtin_amdgcn_sched_barrier(0);
        __builtin_amdgcn_s_setprio(1);
#pragma unroll
        for (int ks = 0; ks < 2; ks++)
#pragma unroll
            for (int m = 0; m < 4; m++)
#pragma unroll
                for (int n = 0; n < 2; n++)
                    acc[m][2 + n] = __builtin_amdgcn_mfma_i32_16x16x64_i8(a[m][ks], b1[n][ks], acc[m][2 + n], 0, 0, 0);
        __builtin_amdgcn_s_setprio(0);
#pragma unroll
        for (int m = 0; m < 4; m++) {
            a[m][0] = *(const v4i*)(lds + bb + aBase + 8192u + ((unsigned)m << 11) + cks0);
            a[m][1] = *(const v4i*)(lds + bb + aBase + 8192u + ((unsigned)m << 11) + cks1);
        }

        // ===== ph3: read-free. barrier; lgkm(0); MFMA q(1,1). =====
        __builtin_amdgcn_s_barrier();
        asm volatile("s_waitcnt lgkmcnt(0)" ::: "memory");
        __builtin_amdgcn_sched_barrier(0);
        __builtin_amdgcn_s_setprio(1);
#pragma unroll
        for (int ks = 0; ks < 2; ks++)
#pragma unroll
            for (int m = 0; m < 4; m++)
#pragma unroll
                for (int n = 0; n < 2; n++)
                    acc[4 + m][2 + n] = __builtin_amdgcn_mfma_i32_16x16x64_i8(a[m][ks], b1[n][ks], acc[4 + m][2 + n], 0, 0, 0);
        __builtin_amdgcn_s_setprio(0);

        // ===== ph4: stage B-h0+A-h0+B-h1(T+2); vmcnt(6); MFMA q(1,0) =====
        stageB(0, T + 2, kT2);
        stageA(0, T + 2, kT2);
        stageB(1, T + 2, kT2);
        asm volatile("s_waitcnt vmcnt(6)" ::: "memory");  // retires all of tile T+1
        __builtin_amdgcn_s_barrier();
        __builtin_amdgcn_s_setprio(1);
#pragma unroll
        for (int ks = 0; ks < 2; ks++)
#pragma unroll
            for (int m = 0; m < 4; m++)
#pragma unroll
                for (int n = 0; n < 2; n++)
                    acc[4 + m][n] = __builtin_amdgcn_mfma_i32_16x16x64_i8(a[m][ks], b0[n][ks], acc[4 + m][n], 0, 0, 0);
        __builtin_amdgcn_s_setprio(0);
        // (no post-MFMA barrier: next ph1's reads of T+1 are safe — vmcnt(6)
        //  before this phase's collective barrier retired all of tile T+1)
    }

    // ---- epilogue: y = acc * (a_scale * w_scale[col]) + bias[col] ----
    float a_s = fmaxf(__uint_as_float(*amax) / QMAX_F, EPS_F);
    const int row0 = bm * BM + wr * 128;
    const int col0 = bn * BN + wc * 64;
#pragma unroll
    for (int n = 0; n < 4; n++) {
        int col = col0 + n * 16 + rA;
        float f = a_s * w_scale[col];
        float bv = bias[col];
#pragma unroll
        for (int m = 0; m < 8; m++) {
            int row = row0 + m * 16 + (kg << 2);
            size_t base = (size_t)row * N + col;
#pragma unroll
            for (int j = 0; j < 4; j++)
                out[base + (size_t)j * N] = (float)acc[m][n][j] * f + bv;
        }
    }
}

extern "C" void kernel_launch(void* const* d_in, const int* in_sizes, int n_in,
                              void* d_out, int out_size, void* d_ws, size_t ws_size,
                              hipStream_t stream) {
    const float* x = (const float*)d_in[0];
    const float* w = (const float*)d_in[1];
    const float* bias = (const float*)d_in[2];
    float* out = (float*)d_out;

    const int N = in_sizes[2];      // 4096
    const int K = in_sizes[1] / N;  // 4096
    const int M = in_sizes[0] / K;  // 16384

    char* ws = (char*)d_ws;
    unsigned* amax = (unsigned*)ws;
    float* w_scale = (float*)(ws + WSCALE_OFF);
    char* xq = ws + XQ_OFF;
    char* wq = ws + XQ_OFF + (size_t)M * K;

    size_t needed = XQ_OFF + (size_t)M * K + (size_t)N * K;
    if (ws_size < needed) return;

    hipMemsetAsync(amax, 0, 4, stream);

    int n4x = (M * K) / 4;
    prep_kernel<<<N, 256, 0, stream>>>((const float4*)x, n4x, (const float4*)w,
                                       (int*)wq, w_scale, K / 4, amax);
    quantx_kernel<<<2048, 256, 0, stream>>>((const float4*)x, amax, (int*)xq, n4x);

    int grid = (M / BM) * (N / BN);  // 64*16 = 1024
    gemm_i8_8ph<<<grid, 512, 0, stream>>>(xq, wq, w_scale, amax, bias, out, M, N, K);
}